// Round 10
// baseline (6174.309 us; speedup 1.0000x reference)
//
#include <hip/hip_runtime.h>
#include <hip/hip_bf16.h>

typedef __attribute__((ext_vector_type(8))) short short8;
typedef __attribute__((ext_vector_type(8))) unsigned short ushort8;
typedef __attribute__((ext_vector_type(4))) float f32x4;
typedef __attribute__((ext_vector_type(4))) int int4v;
typedef __attribute__((ext_vector_type(4))) short short4v;

#define NB 256      // batch rows
#define NS 256      // timesteps
#define NH 512      // hidden/state dim (D == H == 512)
#define NOUT 128
#define XROW 513    // x last-dim stride

#define NCL 8       // clusters (each: 32 rows, 2 groups of 16)
#define RPC 16      // rows per GROUP
#define BPC 4       // blocks per cluster
#define UBS 128     // u-dims per block
#define LPAD 520    // padded LDS row (bf16): 1040B stride

// ---- workspace layout (bytes) ----
#define OFF_DTS   0
#define OFF_Y0    4096
#define OFF_U0    (OFF_Y0 + NB*NH*4)
#define OFF_M     (OFF_U0 + NB*NH*4)
#define OFF_C     (OFF_M + NH*NH*2)
#define OFF_P     (OFF_C + 4096)
#define OFF_HG    (OFF_P + NOUT*NH*4)     // 8 cl * 2 grp * 2 par * 16*512 bf16 = 1 MB
#define HG_BYTES  (NCL*2*2*RPC*NH*2)
#define OFF_HACC  (OFF_HG + HG_BYTES)
#define OFF_FLAGS (OFF_HACC + NB*NH*4)    // (cl*2+g)*32 words; 2 KB

static __device__ __forceinline__ unsigned bf16bits(float x) {
  return (unsigned)__builtin_bit_cast(unsigned short, __float2bfloat16(x));
}

// Cross-block traffic: sc0 sc1 (device coherence point) — R4-proven primitives.
static __device__ __forceinline__ void g_store8(void* addr, short4v v) {
  asm volatile("global_store_dwordx2 %0, %1, off sc0 sc1" :: "v"(addr), "v"(v) : "memory");
}
static __device__ __forceinline__ void g_store4(void* addr, unsigned v) {
  asm volatile("global_store_dword %0, %1, off sc0 sc1" :: "v"(addr), "v"(v) : "memory");
}
static __device__ __forceinline__ unsigned g_load4w(const void* addr) {  // fused load+wait
  unsigned v;
  asm volatile("global_load_dword %0, %1, off sc0 sc1\n\ts_waitcnt vmcnt(0)"
               : "=v"(v) : "v"(addr) : "memory");
  return v;
}
static __device__ __forceinline__ int4v g_load16(const void* addr) {  // no wait
  int4v v;
  asm volatile("global_load_dwordx4 %0, %1, off sc0 sc1" : "=v"(v) : "v"(addr) : "memory");
  return v;
}
static __device__ __forceinline__ void wait_vm0() {
  asm volatile("s_waitcnt vmcnt(0)" ::: "memory");
}

// fast tanh: (e^{2x}-1)/(e^{2x}+1), clamp |x|<=15  (R4-proven accuracy)
static __device__ __forceinline__ float tanh_fast(float x) {
  x = fminf(fmaxf(x, -15.f), 15.f);
  float e = __expf(2.f * x);
  return (e - 1.f) * __builtin_amdgcn_rcpf(e + 1.f);
}

// -------------------- small prep kernels --------------------

__global__ void k_dts(const float* __restrict__ x, float* __restrict__ dts) {
  int s = threadIdx.x;
  if (s < NS - 1) dts[s] = x[(s + 1) * XROW] - x[s * XROW];
  if (s == NS - 1) dts[NS - 1] = x[(NS - 1) * XROW] - x[0];  // sum_dt (telescoping)
}

__global__ void k_y0(const float* __restrict__ x, float* __restrict__ y0) {
  int b = blockIdx.x;
  const float* src = x + (size_t)b * NS * XROW + (size_t)(NS - 1) * XROW + 1;
  for (int d = threadIdx.x; d < NH; d += blockDim.x) y0[b * NH + d] = src[d];
}

__global__ void k_c(const float* __restrict__ W1, const float* __restrict__ b2,
                    float* __restrict__ c) {
  int i = blockIdx.x * blockDim.x + threadIdx.x;
  if (i < NH) {
    float s = 0.f;
    for (int d = 0; d < NH; ++d) s += W1[i * NH + d] * b2[d];
    c[i] = s;
  }
}

__global__ void k_mm_nn_bf16(const float* __restrict__ A, const float* __restrict__ Bm,
                             __hip_bfloat16* __restrict__ C, int N, int K) {
  __shared__ float As[16][17], Bs[16][17];
  int tx = threadIdx.x & 15, ty = threadIdx.x >> 4;
  int m = blockIdx.y * 16 + ty, n = blockIdx.x * 16 + tx;
  float acc = 0.f;
  for (int k0 = 0; k0 < K; k0 += 16) {
    As[ty][tx] = A[m * K + k0 + tx];
    Bs[ty][tx] = Bm[(size_t)(k0 + ty) * N + n];
    __syncthreads();
#pragma unroll
    for (int kk = 0; kk < 16; ++kk) acc += As[ty][kk] * Bs[kk][tx];
    __syncthreads();
  }
  C[m * N + n] = __float2bfloat16(acc);
}

__global__ void k_mm_nn_f32(const float* __restrict__ A, const float* __restrict__ Bm,
                            float* __restrict__ C, int N, int K) {
  __shared__ float As[16][17], Bs[16][17];
  int tx = threadIdx.x & 15, ty = threadIdx.x >> 4;
  int m = blockIdx.y * 16 + ty, n = blockIdx.x * 16 + tx;
  float acc = 0.f;
  for (int k0 = 0; k0 < K; k0 += 16) {
    As[ty][tx] = A[m * K + k0 + tx];
    Bs[ty][tx] = Bm[(size_t)(k0 + ty) * N + n];
    __syncthreads();
#pragma unroll
    for (int kk = 0; kk < 16; ++kk) acc += As[ty][kk] * Bs[kk][tx];
    __syncthreads();
  }
  C[m * N + n] = acc;
}

__global__ void k_mm_nt_f32(const float* __restrict__ A, const float* __restrict__ Bm,
                            float* __restrict__ C, int N, int K) {
  __shared__ float As[16][17], Bs[16][17];
  int tx = threadIdx.x & 15, ty = threadIdx.x >> 4;
  int m = blockIdx.y * 16 + ty;
  int n0 = blockIdx.x * 16;
  float acc = 0.f;
  for (int k0 = 0; k0 < K; k0 += 16) {
    As[ty][tx] = A[m * K + k0 + tx];
    Bs[ty][tx] = Bm[(size_t)(n0 + ty) * K + k0 + tx];
    __syncthreads();
#pragma unroll
    for (int kk = 0; kk < 16; ++kk) acc += As[ty][kk] * Bs[tx][kk];
    __syncthreads();
  }
  C[m * N + n0 + tx] = acc;
}

// -------------------- main ODE integration kernel --------------------
// 32 blocks = 8 clusters x 4 (members share bid mod 8 -> same XCD heuristic).
// Cluster owns 32 batch rows = 2 pipelined groups (A: rows 0-15, B: 16-31).
// Protocol per group = R4's PROVEN shape verbatim: bf16 publish stores ->
// vmcnt(0) ack -> per-wave monotonic flag -> all-lane fused-load poll ->
// bulk gather (no validation). The two groups interleave so every RTT of one
// group is covered by compute/flight of the other. Flags for BOTH groups are
// stored before ANY poll -> no circular wait (deadlock-free by R4 induction).
// hlds time-shared A then B (5 barriers/superstage).

__global__ __launch_bounds__(256) void k_main(
    const float* __restrict__ u0, const __hip_bfloat16* __restrict__ Mg,
    const float* __restrict__ cg, const float* __restrict__ b1g,
    const float* __restrict__ dtsg,
    __hip_bfloat16* __restrict__ hG, float* __restrict__ Hacc,
    unsigned int* __restrict__ flags)
{
  __shared__ __hip_bfloat16 Mlds[UBS][LPAD];   // 130 KB
  __shared__ __hip_bfloat16 hlds[RPC][LPAD];   // 16.25 KB (time-shared A/B)
  __shared__ float dtl[NS];

  const int tid = threadIdx.x;
  const int bx = blockIdx.x;
  const int cl = bx & 7, jb = bx >> 3;        // 4 members: bx = cl, cl+8, cl+16, cl+24
  const int lane = tid & 63, wv = tid >> 6;
  const int r = lane & 15, g4 = lane >> 4;
  const int row0 = cl * 32;
  const int ub = jb * UBS;
  const int rr = tid >> 4, sl = tid & 15;     // gather assignment

  // stage M slice into LDS (rows [ub, ub+128) of M)
  for (int i = tid; i < UBS * 64; i += 256) {
    int row = i >> 6, ch = (i & 63) * 8;
    *(ushort8*)&Mlds[row][ch] = *(const ushort8*)(Mg + (size_t)(ub + row) * NH + ch);
  }
  if (tid < NS) dtl[tid] = dtsg[tid];

  // per-lane state (udim = ub + udl0 + t*16 + j); rows: A = row0+r, B = row0+16+r
  const int udl0 = wv * 32 + g4 * 4;
  float uA[2][4], WaA[2][4], HsA[2][4], HtA[2][4], hrA[2][4], wpA[2][4];
  float uB[2][4], WaB[2][4], HsB[2][4], HtB[2][4], hrB[2][4], wpB[2][4];
  float b1r[2][4], cr[2][4];
#pragma unroll
  for (int t = 0; t < 2; ++t)
#pragma unroll
    for (int j = 0; j < 4; ++j) {
      int ud = ub + udl0 + t * 16 + j;
      b1r[t][j] = b1g[ud];
      cr[t][j] = cg[ud];
      uA[t][j] = u0[(row0 + r) * NH + ud];
      uB[t][j] = u0[(row0 + 16 + r) * NH + ud];
      HtA[t][j] = 0.f; wpA[t][j] = 0.f; WaA[t][j] = 0.f; HsA[t][j] = 0.f;
      HtB[t][j] = 0.f; wpB[t][j] = 0.f; WaB[t][j] = 0.f; HsB[t][j] = 0.f;
    }

  // flag layout: flags[(cl*2+g)*32 + jb*4 + wv]
  unsigned int* flgA = flags + (cl * 2 + 0) * 32;
  unsigned int* flgB = flags + (cl * 2 + 1) * 32;
  // hG layout: [(cl*2+g)*2 + par] chunks of RPC*NH bf16
  auto hbuf = [&](int g, int par) {
    return hG + (size_t)((cl * 2 + g) * 2 + par) * RPC * NH;
  };

  // publish group h: bf16 stores to global + (optional) own LDS cols
  auto pub_g = [&](float hr[2][4], __hip_bfloat16* hgp, bool to_lds) {
#pragma unroll
    for (int t = 0; t < 2; ++t) {
      int col = ub + udl0 + t * 16;
      short4v pk;
      pk.x = (short)bf16bits(hr[t][0]);
      pk.y = (short)bf16bits(hr[t][1]);
      pk.z = (short)bf16bits(hr[t][2]);
      pk.w = (short)bf16bits(hr[t][3]);
      g_store8(hgp + r * NH + col, pk);
      if (to_lds) *(short4v*)&hlds[r][col] = pk;
    }
  };
  // all-lane poll of 16 per-wave flags (R4-proven)
  auto poll = [&](unsigned int* flg, unsigned tgt) {
    const unsigned int* fp = flg + (lane & 15);
    for (;;) {
      unsigned v = g_load4w(fp);
      if (__all((int)(v >= tgt))) break;
      __builtin_amdgcn_s_sleep(1);
    }
  };
  // gather 3 remote 4KB chunks into LDS (tight issue->wait->use; R4-proven)
  auto gather = [&](__hip_bfloat16* hgp) {
    int4v dv[3];
#pragma unroll
    for (int m = 0; m < 3; ++m) {
      int jr = (jb + 1 + m) & 3;
      dv[m] = g_load16(hgp + rr * NH + jr * UBS + sl * 8);
    }
    wait_vm0();
#pragma unroll
    for (int m = 0; m < 3; ++m) {
      int jr = (jb + 1 + m) & 3;
      *(int4v*)&hlds[rr][jr * UBS + sl * 8] = dv[m];
    }
  };

  // ---- prologue: h_A(0) ----
#pragma unroll
  for (int t = 0; t < 2; ++t)
#pragma unroll
    for (int j = 0; j < 4; ++j)
      hrA[t][j] = tanh_fast(uA[t][j] + b1r[t][j]);
  pub_g(hrA, hbuf(0, 0), true);

#pragma unroll 1
  for (int sidx = 0; sidx < 4 * (NS - 1); ++sidx) {
    int st = sidx & 3, step = sidx >> 2;
    float dt = dtl[step];
    float gam = (st == 0) ? 0.f : ((st == 3) ? dt : 0.5f * dt);
    unsigned tgt = (unsigned)(sidx + 1);
    int par = sidx & 1;
    __hip_bfloat16* hgpA = hbuf(0, par);
    __hip_bfloat16* hgpB = hbuf(1, par);

    __syncthreads();   // bar1: A own h in LDS visible (+ prev B reads done via bar5)

    // own-k MFMA A
    f32x4 a0A = {0.f, 0.f, 0.f, 0.f}, a1A = {0.f, 0.f, 0.f, 0.f};
#pragma unroll
    for (int q = 0; q < 4; ++q) {
      int kc = ub + q * 32 + g4 * 8;
      short8 bf = *(const short8*)&hlds[r][kc];
      short8 m0 = *(const short8*)&Mlds[wv * 32 + r][kc];
      short8 m1 = *(const short8*)&Mlds[wv * 32 + 16 + r][kc];
      a0A = __builtin_amdgcn_mfma_f32_16x16x32_bf16(m0, bf, a0A, 0, 0, 0);
      a1A = __builtin_amdgcn_mfma_f32_16x16x32_bf16(m1, bf, a1A, 0, 0, 0);
    }

    // tanh + publish B (stores only; hlds still A's) — covers A store drain
#pragma unroll
    for (int t = 0; t < 2; ++t)
#pragma unroll
      for (int j = 0; j < 4; ++j)
        hrB[t][j] = tanh_fast(uB[t][j] + gam * wpB[t][j] + b1r[t][j]);
    pub_g(hrB, hgpB, false);

    // single ack covers A+B data stores; then BOTH flags (release for both)
    wait_vm0();
    if (lane == 0) {
      g_store4(flgA + jb * 4 + wv, tgt);
      g_store4(flgB + jb * 4 + wv, tgt);
    }

    // A: poll -> gather
    poll(flgA, tgt);
    gather(hgpA);
    __syncthreads();   // bar2: A hlds complete

    // remote-k MFMA A + RK4 A
#pragma unroll 1
    for (int m = 0; m < 3; ++m) {
      int jr = (jb + 1 + m) & 3;
#pragma unroll
      for (int q = 0; q < 4; ++q) {
        int kc = jr * UBS + q * 32 + g4 * 8;
        short8 bf = *(const short8*)&hlds[r][kc];
        short8 m0 = *(const short8*)&Mlds[wv * 32 + r][kc];
        short8 m1 = *(const short8*)&Mlds[wv * 32 + 16 + r][kc];
        a0A = __builtin_amdgcn_mfma_f32_16x16x32_bf16(m0, bf, a0A, 0, 0, 0);
        a1A = __builtin_amdgcn_mfma_f32_16x16x32_bf16(m1, bf, a1A, 0, 0, 0);
      }
    }
    {
      float wc[2][4];
#pragma unroll
      for (int j = 0; j < 4; ++j) { wc[0][j] = a0A[j] + cr[0][j]; wc[1][j] = a1A[j] + cr[1][j]; }
      float cw = (st == 0 || st == 3) ? 1.f : 2.f;
#pragma unroll
      for (int t = 0; t < 2; ++t)
#pragma unroll
        for (int j = 0; j < 4; ++j) {
          if (st == 0) { WaA[t][j] = wc[t][j]; HsA[t][j] = hrA[t][j]; }
          else { WaA[t][j] += cw * wc[t][j]; HsA[t][j] += cw * hrA[t][j]; }
          wpA[t][j] = wc[t][j];
        }
      if (st == 3) {
        float f6 = dt * (1.f / 6.f);
#pragma unroll
        for (int t = 0; t < 2; ++t)
#pragma unroll
          for (int j = 0; j < 4; ++j) {
            uA[t][j] += f6 * WaA[t][j];
            HtA[t][j] += f6 * HsA[t][j];
          }
      }
    }
    __syncthreads();   // bar3: A hlds reads done

    // B: own h into LDS, poll (flags long landed), gather
#pragma unroll
    for (int t = 0; t < 2; ++t) {
      int col = ub + udl0 + t * 16;
      short4v pk;
      pk.x = (short)bf16bits(hrB[t][0]);
      pk.y = (short)bf16bits(hrB[t][1]);
      pk.z = (short)bf16bits(hrB[t][2]);
      pk.w = (short)bf16bits(hrB[t][3]);
      *(short4v*)&hlds[r][col] = pk;
    }
    poll(flgB, tgt);
    gather(hgpB);
    __syncthreads();   // bar4: B hlds complete

    // full MFMA B (all 4 chunks) + RK4 B
    f32x4 a0B = {0.f, 0.f, 0.f, 0.f}, a1B = {0.f, 0.f, 0.f, 0.f};
#pragma unroll 1
    for (int m = 0; m < 4; ++m) {
      int jr = (jb + m) & 3;
#pragma unroll
      for (int q = 0; q < 4; ++q) {
        int kc = jr * UBS + q * 32 + g4 * 8;
        short8 bf = *(const short8*)&hlds[r][kc];
        short8 m0 = *(const short8*)&Mlds[wv * 32 + r][kc];
        short8 m1 = *(const short8*)&Mlds[wv * 32 + 16 + r][kc];
        a0B = __builtin_amdgcn_mfma_f32_16x16x32_bf16(m0, bf, a0B, 0, 0, 0);
        a1B = __builtin_amdgcn_mfma_f32_16x16x32_bf16(m1, bf, a1B, 0, 0, 0);
      }
    }
    {
      float wc[2][4];
#pragma unroll
      for (int j = 0; j < 4; ++j) { wc[0][j] = a0B[j] + cr[0][j]; wc[1][j] = a1B[j] + cr[1][j]; }
      float cw = (st == 0 || st == 3) ? 1.f : 2.f;
#pragma unroll
      for (int t = 0; t < 2; ++t)
#pragma unroll
        for (int j = 0; j < 4; ++j) {
          if (st == 0) { WaB[t][j] = wc[t][j]; HsB[t][j] = hrB[t][j]; }
          else { WaB[t][j] += cw * wc[t][j]; HsB[t][j] += cw * hrB[t][j]; }
          wpB[t][j] = wc[t][j];
        }
      if (st == 3) {
        float f6 = dt * (1.f / 6.f);
#pragma unroll
        for (int t = 0; t < 2; ++t)
#pragma unroll
          for (int j = 0; j < 4; ++j) {
            uB[t][j] += f6 * WaB[t][j];
            HtB[t][j] += f6 * HsB[t][j];
          }
      }
    }
    __syncthreads();   // bar5: B hlds reads done -> safe to write next A own h

    // next A: tanh + publish (stores + own LDS cols)
    {
      int nsidx = sidx + 1;
      int nst = nsidx & 3, nstep = nsidx >> 2;
      float gamn = (nst == 0) ? 0.f : ((nst == 3) ? dtl[nstep] : 0.5f * dtl[nstep]);
#pragma unroll
      for (int t = 0; t < 2; ++t)
#pragma unroll
        for (int j = 0; j < 4; ++j)
          hrA[t][j] = tanh_fast(uA[t][j] + gamn * wpA[t][j] + b1r[t][j]);
      pub_g(hrA, hbuf(0, nsidx & 1), true);   // final iter: dangling stores, harmless
    }
  }

  // write out H accumulators
#pragma unroll
  for (int t = 0; t < 2; ++t)
#pragma unroll
    for (int j = 0; j < 4; ++j) {
      int ud = ub + udl0 + t * 16 + j;
      Hacc[(row0 + r) * NH + ud] = HtA[t][j];
      Hacc[(row0 + 16 + r) * NH + ud] = HtB[t][j];
    }
}

// -------------------- epilogue --------------------
__global__ void k_epi(const float* __restrict__ y0, const float* __restrict__ Hacc,
                      const float* __restrict__ P, const float* __restrict__ Wout,
                      const float* __restrict__ b2, const float* __restrict__ bout,
                      const float* __restrict__ dtsg, float* __restrict__ out)
{
  __shared__ float ys[NH], hs[NH];
  int rr = blockIdx.x, o = threadIdx.x;
  float sdt = dtsg[NS - 1];
  for (int i = threadIdx.x; i < NH; i += blockDim.x) {
    ys[i] = y0[rr * NH + i] + sdt * b2[i];
    hs[i] = Hacc[rr * NH + i];
  }
  __syncthreads();
  float s = bout[o];
  const float* wr = Wout + o * NH;
  const float* pr = P + o * NH;
  for (int d = 0; d < NH; ++d) s += wr[d] * ys[d];
  for (int h = 0; h < NH; ++h) s += pr[h] * hs[h];
  out[rr * NOUT + o] = s;
}

// -------------------- launch --------------------

extern "C" void kernel_launch(void* const* d_in, const int* in_sizes, int n_in,
                              void* d_out, int out_size, void* d_ws, size_t ws_size,
                              hipStream_t stream) {
  const float* x    = (const float*)d_in[0];
  const float* W1   = (const float*)d_in[1];
  const float* b1   = (const float*)d_in[2];
  const float* W2   = (const float*)d_in[3];
  const float* b2   = (const float*)d_in[4];
  const float* Wout = (const float*)d_in[5];
  const float* bout = (const float*)d_in[6];
  float* out = (float*)d_out;

  char* ws = (char*)d_ws;
  float*          dts  = (float*)(ws + OFF_DTS);
  float*          y0   = (float*)(ws + OFF_Y0);
  float*          u0   = (float*)(ws + OFF_U0);
  __hip_bfloat16* Mbf  = (__hip_bfloat16*)(ws + OFF_M);
  float*          cvec = (float*)(ws + OFF_C);
  float*          P    = (float*)(ws + OFF_P);
  __hip_bfloat16* hG   = (__hip_bfloat16*)(ws + OFF_HG);
  float*          Hac  = (float*)(ws + OFF_HACC);
  unsigned int*   flg  = (unsigned int*)(ws + OFF_FLAGS);

  hipMemsetAsync(flg, 0, NCL * 2 * 32 * 4, stream);  // monotonic flags start at 0

  k_dts<<<1, 256, 0, stream>>>(x, dts);
  k_y0 <<<NB, 256, 0, stream>>>(x, y0);
  k_c  <<<2, 256, 0, stream>>>(W1, b2, cvec);
  k_mm_nn_bf16<<<dim3(32, 32), 256, 0, stream>>>(W1, W2, Mbf, NH, NH);
  k_mm_nt_f32<<<dim3(32, 16), 256, 0, stream>>>(y0, W1, u0, NH, NH);
  k_mm_nn_f32<<<dim3(32, 8), 256, 0, stream>>>(Wout, W2, P, NH, NH);

  k_main<<<NCL * BPC, 256, 0, stream>>>(u0, Mbf, cvec, b1, dts, hG, Hac, flg);

  k_epi<<<NB, NOUT, 0, stream>>>(y0, Hac, P, Wout, b2, bout, dts, out);
}

// Round 11
// 4845.534 us; speedup vs baseline: 1.2742x; 1.2742x over previous
//
#include <hip/hip_runtime.h>
#include <hip/hip_bf16.h>

typedef __attribute__((ext_vector_type(8))) short short8;
typedef __attribute__((ext_vector_type(8))) unsigned short ushort8;
typedef __attribute__((ext_vector_type(4))) float f32x4;
typedef __attribute__((ext_vector_type(4))) int int4v;
typedef __attribute__((ext_vector_type(4))) short short4v;

#define NB 256      // batch rows
#define NS 256      // timesteps
#define NH 512      // hidden/state dim (D == H == 512)
#define NOUT 128
#define XROW 513    // x last-dim stride

#define NCL 16      // clusters
#define RPC 16      // rows per cluster
#define BPC 4       // blocks per cluster
#define UBS 128     // u-dims per block
#define LPAD 520    // padded LDS row (bf16): 1040B stride

// ---- workspace layout (bytes) ----
#define OFF_DTS   0
#define OFF_Y0    4096
#define OFF_U0    (OFF_Y0 + NB*NH*4)
#define OFF_M     (OFF_U0 + NB*NH*4)
#define OFF_C     (OFF_M + NH*NH*2)
#define OFF_P     (OFF_C + 4096)
#define OFF_HG    (OFF_P + NOUT*NH*4)                // 16 cl * 2 par * 16*512 bf16
#define HG_BYTES  (NCL*2*RPC*NH*2)
#define OFF_HACC  (OFF_HG + HG_BYTES)
#define OFF_FLAGS (OFF_HACC + NB*NH*4)               // 16 cl * 32 words

static __device__ __forceinline__ unsigned bf16bits(float x) {
  return (unsigned)__builtin_bit_cast(unsigned short, __float2bfloat16(x));
}

// Cross-block traffic: sc0 sc1 (device coherence point) — R4-proven primitives.
static __device__ __forceinline__ void g_store8(void* addr, short4v v) {
  asm volatile("global_store_dwordx2 %0, %1, off sc0 sc1" :: "v"(addr), "v"(v) : "memory");
}
static __device__ __forceinline__ void g_store4(void* addr, unsigned v) {
  asm volatile("global_store_dword %0, %1, off sc0 sc1" :: "v"(addr), "v"(v) : "memory");
}
static __device__ __forceinline__ unsigned g_load4w(const void* addr) {  // fused load+wait
  unsigned v;
  asm volatile("global_load_dword %0, %1, off sc0 sc1\n\ts_waitcnt vmcnt(0)"
               : "=v"(v) : "v"(addr) : "memory");
  return v;
}
static __device__ __forceinline__ int4v g_load16(const void* addr) {  // no wait
  int4v v;
  asm volatile("global_load_dwordx4 %0, %1, off sc0 sc1" : "=v"(v) : "v"(addr) : "memory");
  return v;
}
static __device__ __forceinline__ void wait_vm0() {
  asm volatile("s_waitcnt vmcnt(0)" ::: "memory");
}
// lgkm-only barrier: LDS visibility WITHOUT draining global stores (vmcnt
// stays outstanding across s_barrier — the AITER counted-vmcnt pattern).
static __device__ __forceinline__ void bar_lgkm() {
  asm volatile("s_waitcnt lgkmcnt(0)" ::: "memory");
  __builtin_amdgcn_s_barrier();
}

// fast tanh: (e^{2x}-1)/(e^{2x}+1), clamp |x|<=15  (R4-proven accuracy)
static __device__ __forceinline__ float tanh_fast(float x) {
  x = fminf(fmaxf(x, -15.f), 15.f);
  float e = __expf(2.f * x);
  return (e - 1.f) * __builtin_amdgcn_rcpf(e + 1.f);
}

// -------------------- small prep kernels --------------------

__global__ void k_dts(const float* __restrict__ x, float* __restrict__ dts) {
  int s = threadIdx.x;
  if (s < NS - 1) dts[s] = x[(s + 1) * XROW] - x[s * XROW];
  if (s == NS - 1) dts[NS - 1] = x[(NS - 1) * XROW] - x[0];  // sum_dt (telescoping)
}

__global__ void k_y0(const float* __restrict__ x, float* __restrict__ y0) {
  int b = blockIdx.x;
  const float* src = x + (size_t)b * NS * XROW + (size_t)(NS - 1) * XROW + 1;
  for (int d = threadIdx.x; d < NH; d += blockDim.x) y0[b * NH + d] = src[d];
}

__global__ void k_c(const float* __restrict__ W1, const float* __restrict__ b2,
                    float* __restrict__ c) {
  int i = blockIdx.x * blockDim.x + threadIdx.x;
  if (i < NH) {
    float s = 0.f;
    for (int d = 0; d < NH; ++d) s += W1[i * NH + d] * b2[d];
    c[i] = s;
  }
}

__global__ void k_mm_nn_bf16(const float* __restrict__ A, const float* __restrict__ Bm,
                             __hip_bfloat16* __restrict__ C, int N, int K) {
  __shared__ float As[16][17], Bs[16][17];
  int tx = threadIdx.x & 15, ty = threadIdx.x >> 4;
  int m = blockIdx.y * 16 + ty, n = blockIdx.x * 16 + tx;
  float acc = 0.f;
  for (int k0 = 0; k0 < K; k0 += 16) {
    As[ty][tx] = A[m * K + k0 + tx];
    Bs[ty][tx] = Bm[(size_t)(k0 + ty) * N + n];
    __syncthreads();
#pragma unroll
    for (int kk = 0; kk < 16; ++kk) acc += As[ty][kk] * Bs[kk][tx];
    __syncthreads();
  }
  C[m * N + n] = __float2bfloat16(acc);
}

__global__ void k_mm_nn_f32(const float* __restrict__ A, const float* __restrict__ Bm,
                            float* __restrict__ C, int N, int K) {
  __shared__ float As[16][17], Bs[16][17];
  int tx = threadIdx.x & 15, ty = threadIdx.x >> 4;
  int m = blockIdx.y * 16 + ty, n = blockIdx.x * 16 + tx;
  float acc = 0.f;
  for (int k0 = 0; k0 < K; k0 += 16) {
    As[ty][tx] = A[m * K + k0 + tx];
    Bs[ty][tx] = Bm[(size_t)(k0 + ty) * N + n];
    __syncthreads();
#pragma unroll
    for (int kk = 0; kk < 16; ++kk) acc += As[ty][kk] * Bs[kk][tx];
    __syncthreads();
  }
  C[m * N + n] = acc;
}

__global__ void k_mm_nt_f32(const float* __restrict__ A, const float* __restrict__ Bm,
                            float* __restrict__ C, int N, int K) {
  __shared__ float As[16][17], Bs[16][17];
  int tx = threadIdx.x & 15, ty = threadIdx.x >> 4;
  int m = blockIdx.y * 16 + ty;
  int n0 = blockIdx.x * 16;
  float acc = 0.f;
  for (int k0 = 0; k0 < K; k0 += 16) {
    As[ty][tx] = A[m * K + k0 + tx];
    Bs[ty][tx] = Bm[(size_t)(n0 + ty) * K + k0 + tx];
    __syncthreads();
#pragma unroll
    for (int kk = 0; kk < 16; ++kk) acc += As[ty][kk] * Bs[tx][kk];
    __syncthreads();
  }
  C[m * N + n0 + tx] = acc;
}

// -------------------- main ODE integration kernel --------------------
// R4's PROVEN protocol (bf16 publish -> ack -> per-wave flag -> all-lane poll
// -> gather, no validation), with three latency squeezes:
//  (1) lgkm-only barriers: publish stores stay in flight across s_barrier;
//      the ack (vmcnt 0) is taken AFTER own-k MFMA -> drain overlaps compute.
//  (2) remote h gathered directly into MFMA B-fragments (12x dwordx4/lane,
//      tight issue->wait->consume) -> no LDS round-trip, no extra barrier.
//  (3) poll with no sleep backoff.
// Per stage: tanh -> publish(global + own LDS) -> lgkm-bar -> own-k MFMA ->
// sched_barrier+ack -> flag -> poll -> direct gather -> remote-k MFMA ->
// RK4 -> lgkm-bar.

__global__ __launch_bounds__(256) void k_main(
    const float* __restrict__ u0, const __hip_bfloat16* __restrict__ Mg,
    const float* __restrict__ cg, const float* __restrict__ b1g,
    const float* __restrict__ dtsg,
    __hip_bfloat16* __restrict__ hG, float* __restrict__ Hacc,
    unsigned int* __restrict__ flags)
{
  __shared__ __hip_bfloat16 Mlds[UBS][LPAD];   // 130 KB
  __shared__ __hip_bfloat16 hlds[RPC][LPAD];   // 16.25 KB (own cols only)
  __shared__ float dtl[NS];

  const int tid = threadIdx.x;
  const int bx = blockIdx.x;
  const int xcd = bx & 7, slot = bx >> 3;
  const int cl = xcd + ((slot >> 2) << 3);   // cluster members share bid mod 8
  const int jb = slot & 3;
  const int lane = tid & 63, wv = tid >> 6;
  const int r = lane & 15, g4 = lane >> 4;
  const int row0 = cl * RPC;
  const int ub = jb * UBS;

  // stage M slice into LDS (rows [ub, ub+128) of M)
  for (int i = tid; i < UBS * 64; i += 256) {
    int row = i >> 6, ch = (i & 63) * 8;
    *(ushort8*)&Mlds[row][ch] = *(const ushort8*)(Mg + (size_t)(ub + row) * NH + ch);
  }
  if (tid < NS) dtl[tid] = dtsg[tid];

  // per-lane state: (udim = ub + udl0 + t*16 + j, batch row = row0 + r)
  const int udl0 = wv * 32 + g4 * 4;
  float u[2][4], Wa[2][4], Hs[2][4], Ht[2][4], hr[2][4], wp[2][4];
  float b1r[2][4], cr[2][4];
#pragma unroll
  for (int t = 0; t < 2; ++t)
#pragma unroll
    for (int j = 0; j < 4; ++j) {
      int ud = ub + udl0 + t * 16 + j;
      u[t][j] = u0[(row0 + r) * NH + ud];
      b1r[t][j] = b1g[ud];
      cr[t][j] = cg[ud];
      Ht[t][j] = 0.f; wp[t][j] = 0.f; Wa[t][j] = 0.f; Hs[t][j] = 0.f;
    }
  __syncthreads();   // M staged (full drain ok, once)

  unsigned int* flg = flags + cl * 32;   // 16 per-wave flag words per cluster

  int sidx = 0;
  for (int step = 0; step < NS - 1; ++step) {
    float dt = dtl[step];
#pragma unroll 1
    for (int st = 0; st < 4; ++st, ++sidx) {
      float gam = (st == 0) ? 0.f : ((st == 3) ? dt : 0.5f * dt);
      // h = tanh(u + gam*w_prev + b1)
#pragma unroll
      for (int t = 0; t < 2; ++t)
#pragma unroll
        for (int j = 0; j < 4; ++j)
          hr[t][j] = tanh_fast(u[t][j] + gam * wp[t][j] + b1r[t][j]);

      int par = sidx & 1;
      __hip_bfloat16* hgp = hG + (size_t)(cl * 2 + par) * RPC * NH;
      // publish own h (global stores stay in flight; LDS for own-k MFMA)
#pragma unroll
      for (int t = 0; t < 2; ++t) {
        short4v pk;
        pk.x = (short)bf16bits(hr[t][0]);
        pk.y = (short)bf16bits(hr[t][1]);
        pk.z = (short)bf16bits(hr[t][2]);
        pk.w = (short)bf16bits(hr[t][3]);
        int col = ub + udl0 + t * 16;
        g_store8(hgp + r * NH + col, pk);
        *(short4v*)&hlds[r][col] = pk;
      }
      bar_lgkm();                // own h visible in LDS; global stores in flight

      // own-k MFMA (publish stores drain underneath)
      f32x4 acc0 = {0.f, 0.f, 0.f, 0.f}, acc1 = {0.f, 0.f, 0.f, 0.f};
#pragma unroll
      for (int q = 0; q < 4; ++q) {
        int kc = ub + q * 32 + g4 * 8;
        short8 bf = *(const short8*)&hlds[r][kc];
        short8 m0 = *(const short8*)&Mlds[wv * 32 + r][kc];
        short8 m1 = *(const short8*)&Mlds[wv * 32 + 16 + r][kc];
        acc0 = __builtin_amdgcn_mfma_f32_16x16x32_bf16(m0, bf, acc0, 0, 0, 0);
        acc1 = __builtin_amdgcn_mfma_f32_16x16x32_bf16(m1, bf, acc1, 0, 0, 0);
      }
      __builtin_amdgcn_sched_barrier(0);   // pin MFMAs before the ack
      wait_vm0();                          // ack residual (mostly drained)
      unsigned tgt = (unsigned)(sidx + 1);
      if (lane == 0) g_store4(flg + jb * 4 + wv, tgt);   // per-wave flag

      // all-lane poll of the 16 wave-flags (no sleep)
      {
        const unsigned int* fp = flg + (lane & 15);
        for (;;) {
          unsigned v = g_load4w(fp);
          if (__all((int)(v >= tgt))) break;
        }
      }

      // direct gather: remote B-fragments straight to registers
      int4v dv[12];
      {
        const __hip_bfloat16* hb = hgp + r * NH;
#pragma unroll
        for (int m = 0; m < 3; ++m) {
          int jr = (jb + 1 + m) & 3;
#pragma unroll
          for (int q = 0; q < 4; ++q)
            dv[m * 4 + q] = g_load16(hb + jr * UBS + q * 32 + g4 * 8);
        }
        wait_vm0();
        __builtin_amdgcn_sched_barrier(0);
      }
      // remote-k MFMA from fragments
#pragma unroll
      for (int m = 0; m < 3; ++m) {
        int jr = (jb + 1 + m) & 3;
#pragma unroll
        for (int q = 0; q < 4; ++q) {
          int kc = jr * UBS + q * 32 + g4 * 8;
          short8 bf = __builtin_bit_cast(short8, dv[m * 4 + q]);
          short8 m0 = *(const short8*)&Mlds[wv * 32 + r][kc];
          short8 m1 = *(const short8*)&Mlds[wv * 32 + 16 + r][kc];
          acc0 = __builtin_amdgcn_mfma_f32_16x16x32_bf16(m0, bf, acc0, 0, 0, 0);
          acc1 = __builtin_amdgcn_mfma_f32_16x16x32_bf16(m1, bf, acc1, 0, 0, 0);
        }
      }

      float wc[2][4];
#pragma unroll
      for (int j = 0; j < 4; ++j) { wc[0][j] = acc0[j] + cr[0][j]; wc[1][j] = acc1[j] + cr[1][j]; }

      // RK4 bookkeeping
      float cw = (st == 0 || st == 3) ? 1.f : 2.f;
#pragma unroll
      for (int t = 0; t < 2; ++t)
#pragma unroll
        for (int j = 0; j < 4; ++j) {
          if (st == 0) { Wa[t][j] = wc[t][j]; Hs[t][j] = hr[t][j]; }
          else { Wa[t][j] += cw * wc[t][j]; Hs[t][j] += cw * hr[t][j]; }
          wp[t][j] = wc[t][j];
        }
      if (st == 3) {
        float f6 = dt * (1.f / 6.f);
#pragma unroll
        for (int t = 0; t < 2; ++t)
#pragma unroll
          for (int j = 0; j < 4; ++j) {
            u[t][j] += f6 * Wa[t][j];
            Ht[t][j] += f6 * Hs[t][j];
          }
      }
      bar_lgkm();   // all waves past own-k MFMA reads -> next publish safe
    }
  }

  // write out H accumulator
#pragma unroll
  for (int t = 0; t < 2; ++t)
#pragma unroll
    for (int j = 0; j < 4; ++j)
      Hacc[(row0 + r) * NH + ub + udl0 + t * 16 + j] = Ht[t][j];
}

// -------------------- epilogue --------------------
__global__ void k_epi(const float* __restrict__ y0, const float* __restrict__ Hacc,
                      const float* __restrict__ P, const float* __restrict__ Wout,
                      const float* __restrict__ b2, const float* __restrict__ bout,
                      const float* __restrict__ dtsg, float* __restrict__ out)
{
  __shared__ float ys[NH], hs[NH];
  int rr = blockIdx.x, o = threadIdx.x;
  float sdt = dtsg[NS - 1];
  for (int i = threadIdx.x; i < NH; i += blockDim.x) {
    ys[i] = y0[rr * NH + i] + sdt * b2[i];
    hs[i] = Hacc[rr * NH + i];
  }
  __syncthreads();
  float s = bout[o];
  const float* wr = Wout + o * NH;
  const float* pr = P + o * NH;
  for (int d = 0; d < NH; ++d) s += wr[d] * ys[d];
  for (int h = 0; h < NH; ++h) s += pr[h] * hs[h];
  out[rr * NOUT + o] = s;
}

// -------------------- launch --------------------

extern "C" void kernel_launch(void* const* d_in, const int* in_sizes, int n_in,
                              void* d_out, int out_size, void* d_ws, size_t ws_size,
                              hipStream_t stream) {
  const float* x    = (const float*)d_in[0];
  const float* W1   = (const float*)d_in[1];
  const float* b1   = (const float*)d_in[2];
  const float* W2   = (const float*)d_in[3];
  const float* b2   = (const float*)d_in[4];
  const float* Wout = (const float*)d_in[5];
  const float* bout = (const float*)d_in[6];
  float* out = (float*)d_out;

  char* ws = (char*)d_ws;
  float*          dts  = (float*)(ws + OFF_DTS);
  float*          y0   = (float*)(ws + OFF_Y0);
  float*          u0   = (float*)(ws + OFF_U0);
  __hip_bfloat16* Mbf  = (__hip_bfloat16*)(ws + OFF_M);
  float*          cvec = (float*)(ws + OFF_C);
  float*          P    = (float*)(ws + OFF_P);
  __hip_bfloat16* hG   = (__hip_bfloat16*)(ws + OFF_HG);
  float*          Hac  = (float*)(ws + OFF_HACC);
  unsigned int*   flg  = (unsigned int*)(ws + OFF_FLAGS);

  hipMemsetAsync(flg, 0, NCL * 32 * 4, stream);   // monotonic flags start at 0

  k_dts<<<1, 256, 0, stream>>>(x, dts);
  k_y0 <<<NB, 256, 0, stream>>>(x, y0);
  k_c  <<<2, 256, 0, stream>>>(W1, b2, cvec);
  k_mm_nn_bf16<<<dim3(32, 32), 256, 0, stream>>>(W1, W2, Mbf, NH, NH);
  k_mm_nt_f32<<<dim3(32, 16), 256, 0, stream>>>(y0, W1, u0, NH, NH);
  k_mm_nn_f32<<<dim3(32, 8), 256, 0, stream>>>(Wout, W2, P, NH, NH);

  k_main<<<NCL * BPC, 256, 0, stream>>>(u0, Mbf, cvec, b1, dts, hG, Hac, flg);

  k_epi<<<NB, NOUT, 0, stream>>>(y0, Hac, P, Wout, b2, bout, dts, out);
}

// Round 13
// 2484.202 us; speedup vs baseline: 2.4854x; 1.9505x over previous
//
#include <hip/hip_runtime.h>
#include <hip/hip_bf16.h>

typedef __attribute__((ext_vector_type(8))) short short8;
typedef __attribute__((ext_vector_type(8))) unsigned short ushort8;
typedef __attribute__((ext_vector_type(4))) float f32x4;
typedef __attribute__((ext_vector_type(4))) int int4v;
typedef __attribute__((ext_vector_type(4))) short short4v;

#define NB 256      // batch rows
#define NS 256      // timesteps
#define NH 512      // hidden/state dim (D == H == 512)
#define NOUT 128
#define XROW 513    // x last-dim stride

#define NCL 16      // clusters
#define RPC 16      // rows per cluster
#define BPC 4       // blocks per cluster
#define UBS 128     // u-dims per block
#define LPAD 520    // padded LDS row (bf16): 1040B stride

// ---- workspace layout (bytes) ----
#define OFF_DTS   0
#define OFF_Y0    4096
#define OFF_U0    (OFF_Y0 + NB*NH*4)
#define OFF_M     (OFF_U0 + NB*NH*4)
#define OFF_C     (OFF_M + NH*NH*2)
#define OFF_P     (OFF_C + 4096)
#define OFF_HG    (OFF_P + NOUT*NH*4)                // 16 cl * 2 par * 16*512 bf16
#define HG_BYTES  (NCL*2*RPC*NH*2)
#define OFF_HACC  (OFF_HG + HG_BYTES)
#define OFF_FLAGS (OFF_HACC + NB*NH*4)               // 16 cl * 32 words

static __device__ __forceinline__ unsigned bf16bits(float x) {
  return (unsigned)__builtin_bit_cast(unsigned short, __float2bfloat16(x));
}

// Cross-block traffic: sc0 sc1 (device coherence point) — R4-proven primitives.
static __device__ __forceinline__ void g_store8(void* addr, short4v v) {
  asm volatile("global_store_dwordx2 %0, %1, off sc0 sc1" :: "v"(addr), "v"(v) : "memory");
}
static __device__ __forceinline__ void g_store4(void* addr, unsigned v) {
  asm volatile("global_store_dword %0, %1, off sc0 sc1" :: "v"(addr), "v"(v) : "memory");
}
static __device__ __forceinline__ unsigned g_load4w(const void* addr) {  // fused load+wait
  unsigned v;
  asm volatile("global_load_dword %0, %1, off sc0 sc1\n\ts_waitcnt vmcnt(0)"
               : "=v"(v) : "v"(addr) : "memory");
  return v;
}
static __device__ __forceinline__ void wait_vm0() {
  asm volatile("s_waitcnt vmcnt(0)" ::: "memory");
}

// fast tanh: (e^{2x}-1)/(e^{2x}+1), clamp |x|<=15  (R4-proven accuracy)
static __device__ __forceinline__ float tanh_fast(float x) {
  x = fminf(fmaxf(x, -15.f), 15.f);
  float e = __expf(2.f * x);
  return (e - 1.f) * __builtin_amdgcn_rcpf(e + 1.f);
}

// -------------------- small prep kernels --------------------

__global__ void k_dts(const float* __restrict__ x, float* __restrict__ dts) {
  int s = threadIdx.x;
  if (s < NS - 1) dts[s] = x[(s + 1) * XROW] - x[s * XROW];
  if (s == NS - 1) dts[NS - 1] = x[(NS - 1) * XROW] - x[0];  // sum_dt (telescoping)
}

__global__ void k_y0(const float* __restrict__ x, float* __restrict__ y0) {
  int b = blockIdx.x;
  const float* src = x + (size_t)b * NS * XROW + (size_t)(NS - 1) * XROW + 1;
  for (int d = threadIdx.x; d < NH; d += blockDim.x) y0[b * NH + d] = src[d];
}

__global__ void k_c(const float* __restrict__ W1, const float* __restrict__ b2,
                    float* __restrict__ c) {
  int i = blockIdx.x * blockDim.x + threadIdx.x;
  if (i < NH) {
    float s = 0.f;
    for (int d = 0; d < NH; ++d) s += W1[i * NH + d] * b2[d];
    c[i] = s;
  }
}

__global__ void k_mm_nn_bf16(const float* __restrict__ A, const float* __restrict__ Bm,
                             __hip_bfloat16* __restrict__ C, int N, int K) {
  __shared__ float As[16][17], Bs[16][17];
  int tx = threadIdx.x & 15, ty = threadIdx.x >> 4;
  int m = blockIdx.y * 16 + ty, n = blockIdx.x * 16 + tx;
  float acc = 0.f;
  for (int k0 = 0; k0 < K; k0 += 16) {
    As[ty][tx] = A[m * K + k0 + tx];
    Bs[ty][tx] = Bm[(size_t)(k0 + ty) * N + n];
    __syncthreads();
#pragma unroll
    for (int kk = 0; kk < 16; ++kk) acc += As[ty][kk] * Bs[kk][tx];
    __syncthreads();
  }
  C[m * N + n] = __float2bfloat16(acc);
}

__global__ void k_mm_nn_f32(const float* __restrict__ A, const float* __restrict__ Bm,
                            float* __restrict__ C, int N, int K) {
  __shared__ float As[16][17], Bs[16][17];
  int tx = threadIdx.x & 15, ty = threadIdx.x >> 4;
  int m = blockIdx.y * 16 + ty, n = blockIdx.x * 16 + tx;
  float acc = 0.f;
  for (int k0 = 0; k0 < K; k0 += 16) {
    As[ty][tx] = A[m * K + k0 + tx];
    Bs[ty][tx] = Bm[(size_t)(k0 + ty) * N + n];
    __syncthreads();
#pragma unroll
    for (int kk = 0; kk < 16; ++kk) acc += As[ty][kk] * Bs[kk][tx];
    __syncthreads();
  }
  C[m * N + n] = acc;
}

__global__ void k_mm_nt_f32(const float* __restrict__ A, const float* __restrict__ Bm,
                            float* __restrict__ C, int N, int K) {
  __shared__ float As[16][17], Bs[16][17];
  int tx = threadIdx.x & 15, ty = threadIdx.x >> 4;
  int m = blockIdx.y * 16 + ty;
  int n0 = blockIdx.x * 16;
  float acc = 0.f;
  for (int k0 = 0; k0 < K; k0 += 16) {
    As[ty][tx] = A[m * K + k0 + tx];
    Bs[ty][tx] = Bm[(size_t)(n0 + ty) * K + k0 + tx];
    __syncthreads();
#pragma unroll
    for (int kk = 0; kk < 16; ++kk) acc += As[ty][kk] * Bs[tx][kk];
    __syncthreads();
  }
  C[m * N + n0 + tx] = acc;
}

// -------------------- main ODE integration kernel --------------------
// R4's PROVEN protocol VERBATIM: bf16 publish -> vmcnt(0) ack -> per-wave
// monotonic flag -> barrier -> own-k MFMA -> all-lane fused-load poll ->
// gather -> barrier -> remote-k MFMA -> RK4. Changes vs R4 (local-work only):
//  (1) M held in REGISTERS (Mreg[2][16] short8 = 128 VGPR/wave), statically
//      indexed via chunk reordering (own chunks at i=0..3) -> no Mlds, no
//      A-fragment LDS reads, LDS = 16.5 KB.
//  (2) gather = ONE fused asm (3 loads + vmcnt(0), early-clobber outs) ->
//      no compiler-visible in-flight registers, spill-proof.
//  (3) folded RK4 (du/Ht accumulation).
// Liveness depends only on flag stores/loads (proven); data registers can
// never deadlock the protocol.

__global__ __launch_bounds__(256) void k_main(
    const float* __restrict__ u0, const __hip_bfloat16* __restrict__ Mg,
    const float* __restrict__ cg, const float* __restrict__ b1g,
    const float* __restrict__ dtsg,
    __hip_bfloat16* __restrict__ hG, float* __restrict__ Hacc,
    unsigned int* __restrict__ flags)
{
  __shared__ __hip_bfloat16 hlds[RPC][LPAD];   // 16.25 KB
  __shared__ float dtl[NS];

  const int tid = threadIdx.x;
  const int bx = blockIdx.x;
  const int xcd = bx & 7, slot = bx >> 3;
  const int cl = xcd + ((slot >> 2) << 3);   // cluster members share bid mod 8
  const int jb = slot & 3;
  const int lane = tid & 63, wv = tid >> 6;
  const int r = lane & 15, g4 = lane >> 4;
  const int row0 = cl * RPC;
  const int ub = jb * UBS;
  const int rr = tid >> 4, sl = tid & 15;     // gather assignment

  // ---- M fragments into registers, chunk-reordered: i -> global chunk
  // qg = ((jb + (i>>2)) & 3)*4 + (i&3), so i=0..3 are OWN chunks. ----
  short8 Mreg[2][16];
#pragma unroll
  for (int t = 0; t < 2; ++t)
#pragma unroll
    for (int i = 0; i < 16; ++i) {
      int qg = ((jb + (i >> 2)) & 3) * 4 + (i & 3);
      Mreg[t][i] = *(const short8*)(Mg + (size_t)(ub + wv * 32 + t * 16 + r) * NH
                                    + qg * 32 + g4 * 8);
    }
  if (tid < NS) dtl[tid] = dtsg[tid];

  // per-lane state: (udim = ub + udl0 + t*16 + j, batch row = row0 + r)
  const int udl0 = wv * 32 + g4 * 4;
  float u[2][4], du[2][4], Ht[2][4], hr[2][4], wp[2][4], b1r[2][4], cr[2][4];
#pragma unroll
  for (int t = 0; t < 2; ++t)
#pragma unroll
    for (int j = 0; j < 4; ++j) {
      int ud = ub + udl0 + t * 16 + j;
      u[t][j] = u0[(row0 + r) * NH + ud];
      b1r[t][j] = b1g[ud];
      cr[t][j] = cg[ud];
      Ht[t][j] = 0.f; wp[t][j] = 0.f; du[t][j] = 0.f;
    }
  __syncthreads();

  unsigned int* flg = flags + cl * 32;   // 16 per-wave flag words per cluster

  int sidx = 0;
  for (int step = 0; step < NS - 1; ++step) {
    float dt = dtl[step];
#pragma unroll 1
    for (int st = 0; st < 4; ++st, ++sidx) {
      float gam = (st == 0) ? 0.f : ((st == 3) ? dt : 0.5f * dt);
      // h = tanh(u + gam*w_prev + b1)
#pragma unroll
      for (int t = 0; t < 2; ++t)
#pragma unroll
        for (int j = 0; j < 4; ++j)
          hr[t][j] = tanh_fast(u[t][j] + gam * wp[t][j] + b1r[t][j]);

      int par = sidx & 1;
      __hip_bfloat16* hgp = hG + (size_t)(cl * 2 + par) * RPC * NH;
      // publish own h (global, for peers) + LDS (for own-k MFMA)
#pragma unroll
      for (int t = 0; t < 2; ++t) {
        short4v pk;
        pk.x = (short)bf16bits(hr[t][0]);
        pk.y = (short)bf16bits(hr[t][1]);
        pk.z = (short)bf16bits(hr[t][2]);
        pk.w = (short)bf16bits(hr[t][3]);
        int col = ub + udl0 + t * 16;
        g_store8(hgp + r * NH + col, pk);
        *(short4v*)&hlds[r][col] = pk;
      }
      wait_vm0();                          // ack: own data at coherence point
      unsigned tgt = (unsigned)(sidx + 1);
      if (lane == 0) g_store4(flg + jb * 4 + wv, tgt);   // per-wave flag
      __syncthreads();                     // own h visible in LDS

      // own-k MFMA (A from registers; overlaps peers' flag/data flight)
      f32x4 acc0 = {0.f, 0.f, 0.f, 0.f}, acc1 = {0.f, 0.f, 0.f, 0.f};
#pragma unroll
      for (int i = 0; i < 4; ++i) {
        int kc = ub + i * 32 + g4 * 8;
        short8 bf = *(const short8*)&hlds[r][kc];
        acc0 = __builtin_amdgcn_mfma_f32_16x16x32_bf16(Mreg[0][i], bf, acc0, 0, 0, 0);
        acc1 = __builtin_amdgcn_mfma_f32_16x16x32_bf16(Mreg[1][i], bf, acc1, 0, 0, 0);
      }

      // all-lane poll of the 16 wave-flags (R4-proven)
      {
        const unsigned int* fp = flg + (lane & 15);
        for (;;) {
          unsigned v = g_load4w(fp);
          if (__all((int)(v >= tgt))) break;
          __builtin_amdgcn_s_sleep(1);
        }
      }

      // gather 3 remote 4KB chunks: ONE fused asm (loads + wait), then LDS
      {
        int4v d0, d1, d2;
        const __hip_bfloat16* hb = hgp + rr * NH;
        const void* a0 = hb + ((jb + 1) & 3) * UBS + sl * 8;
        const void* a1 = hb + ((jb + 2) & 3) * UBS + sl * 8;
        const void* a2 = hb + ((jb + 3) & 3) * UBS + sl * 8;
        asm volatile(
            "global_load_dwordx4 %0, %3, off sc0 sc1\n\t"
            "global_load_dwordx4 %1, %4, off sc0 sc1\n\t"
            "global_load_dwordx4 %2, %5, off sc0 sc1\n\t"
            "s_waitcnt vmcnt(0)"
            : "=&v"(d0), "=&v"(d1), "=&v"(d2)
            : "v"(a0), "v"(a1), "v"(a2)
            : "memory");
        *(int4v*)&hlds[rr][((jb + 1) & 3) * UBS + sl * 8] = d0;
        *(int4v*)&hlds[rr][((jb + 2) & 3) * UBS + sl * 8] = d1;
        *(int4v*)&hlds[rr][((jb + 3) & 3) * UBS + sl * 8] = d2;
      }
      __syncthreads();                     // remote h visible

      // remote-k MFMA (A from registers, static indices)
#pragma unroll
      for (int m = 1; m < 4; ++m) {
        int jr = (jb + m) & 3;
#pragma unroll
        for (int qq = 0; qq < 4; ++qq) {
          int kc = jr * UBS + qq * 32 + g4 * 8;
          short8 bf = *(const short8*)&hlds[r][kc];
          acc0 = __builtin_amdgcn_mfma_f32_16x16x32_bf16(Mreg[0][m * 4 + qq], bf, acc0, 0, 0, 0);
          acc1 = __builtin_amdgcn_mfma_f32_16x16x32_bf16(Mreg[1][m * 4 + qq], bf, acc1, 0, 0, 0);
        }
      }

      // folded RK4: du += cw*w ; Ht += (dt/6)*cw*h ; wp = w ; st3: u += (dt/6)*du
      {
        float cw = (st == 0 || st == 3) ? 1.f : 2.f;
        float f6 = dt * (1.f / 6.f);
        float f6c = f6 * cw;
#pragma unroll
        for (int j = 0; j < 4; ++j) {
          float w0 = acc0[j] + cr[0][j];
          float w1 = acc1[j] + cr[1][j];
          du[0][j] = (st == 0) ? w0 : du[0][j] + cw * w0;
          du[1][j] = (st == 0) ? w1 : du[1][j] + cw * w1;
          Ht[0][j] += f6c * hr[0][j];
          Ht[1][j] += f6c * hr[1][j];
          wp[0][j] = w0;
          wp[1][j] = w1;
        }
        if (st == 3) {
#pragma unroll
          for (int t = 0; t < 2; ++t)
#pragma unroll
            for (int j = 0; j < 4; ++j)
              u[t][j] += f6 * du[t][j];
        }
      }
    }
  }

  // write out H accumulator
#pragma unroll
  for (int t = 0; t < 2; ++t)
#pragma unroll
    for (int j = 0; j < 4; ++j)
      Hacc[(row0 + r) * NH + ub + udl0 + t * 16 + j] = Ht[t][j];
}

// -------------------- epilogue --------------------
__global__ void k_epi(const float* __restrict__ y0, const float* __restrict__ Hacc,
                      const float* __restrict__ P, const float* __restrict__ Wout,
                      const float* __restrict__ b2, const float* __restrict__ bout,
                      const float* __restrict__ dtsg, float* __restrict__ out)
{
  __shared__ float ys[NH], hs[NH];
  int rr = blockIdx.x, o = threadIdx.x;
  float sdt = dtsg[NS - 1];
  for (int i = threadIdx.x; i < NH; i += blockDim.x) {
    ys[i] = y0[rr * NH + i] + sdt * b2[i];
    hs[i] = Hacc[rr * NH + i];
  }
  __syncthreads();
  float s = bout[o];
  const float* wr = Wout + o * NH;
  const float* pr = P + o * NH;
  for (int d = 0; d < NH; ++d) s += wr[d] * ys[d];
  for (int h = 0; h < NH; ++h) s += pr[h] * hs[h];
  out[rr * NOUT + o] = s;
}

// -------------------- launch --------------------

extern "C" void kernel_launch(void* const* d_in, const int* in_sizes, int n_in,
                              void* d_out, int out_size, void* d_ws, size_t ws_size,
                              hipStream_t stream) {
  const float* x    = (const float*)d_in[0];
  const float* W1   = (const float*)d_in[1];
  const float* b1   = (const float*)d_in[2];
  const float* W2   = (const float*)d_in[3];
  const float* b2   = (const float*)d_in[4];
  const float* Wout = (const float*)d_in[5];
  const float* bout = (const float*)d_in[6];
  float* out = (float*)d_out;

  char* ws = (char*)d_ws;
  float*          dts  = (float*)(ws + OFF_DTS);
  float*          y0   = (float*)(ws + OFF_Y0);
  float*          u0   = (float*)(ws + OFF_U0);
  __hip_bfloat16* Mbf  = (__hip_bfloat16*)(ws + OFF_M);
  float*          cvec = (float*)(ws + OFF_C);
  float*          P    = (float*)(ws + OFF_P);
  __hip_bfloat16* hG   = (__hip_bfloat16*)(ws + OFF_HG);
  float*          Hac  = (float*)(ws + OFF_HACC);
  unsigned int*   flg  = (unsigned int*)(ws + OFF_FLAGS);

  hipMemsetAsync(flg, 0, NCL * 32 * 4, stream);   // monotonic flags start at 0

  k_dts<<<1, 256, 0, stream>>>(x, dts);
  k_y0 <<<NB, 256, 0, stream>>>(x, y0);
  k_c  <<<2, 256, 0, stream>>>(W1, b2, cvec);
  k_mm_nn_bf16<<<dim3(32, 32), 256, 0, stream>>>(W1, W2, Mbf, NH, NH);
  k_mm_nt_f32<<<dim3(32, 16), 256, 0, stream>>>(y0, W1, u0, NH, NH);
  k_mm_nn_f32<<<dim3(32, 8), 256, 0, stream>>>(Wout, W2, P, NH, NH);

  k_main<<<NCL * BPC, 256, 0, stream>>>(u0, Mbf, cvec, b1, dts, hG, Hac, flg);

  k_epi<<<NB, NOUT, 0, stream>>>(y0, Hac, P, Wout, b2, bout, dts, out);
}

// Round 14
// 2462.146 us; speedup vs baseline: 2.5077x; 1.0090x over previous
//
#include <hip/hip_runtime.h>
#include <hip/hip_bf16.h>

typedef __attribute__((ext_vector_type(8))) short short8;
typedef __attribute__((ext_vector_type(8))) unsigned short ushort8;
typedef __attribute__((ext_vector_type(4))) float f32x4;
typedef __attribute__((ext_vector_type(4))) int int4v;
typedef __attribute__((ext_vector_type(4))) short short4v;

#define NB 256      // batch rows
#define NS 256      // timesteps
#define NH 512      // hidden/state dim (D == H == 512)
#define NOUT 128
#define XROW 513    // x last-dim stride

#define NCL 16      // clusters
#define RPC 16      // rows per cluster
#define BPC 4       // blocks per cluster
#define UBS 128     // u-dims per block
#define LPAD 520    // padded LDS row (bf16): 1040B stride

// ---- workspace layout (bytes) ----
#define OFF_DTS   0
#define OFF_Y0    4096
#define OFF_U0    (OFF_Y0 + NB*NH*4)
#define OFF_M     (OFF_U0 + NB*NH*4)
#define OFF_C     (OFF_M + NH*NH*2)
#define OFF_P     (OFF_C + 4096)
#define OFF_HG    (OFF_P + NOUT*NH*4)                // 16 cl * 2 par * 16*512 bf16
#define HG_BYTES  (NCL*2*RPC*NH*2)
#define OFF_HACC  (OFF_HG + HG_BYTES)
#define OFF_FLAGS (OFF_HACC + NB*NH*4)               // 16 cl * 32 words

static __device__ __forceinline__ unsigned bf16bits(float x) {
  return (unsigned)__builtin_bit_cast(unsigned short, __float2bfloat16(x));
}

// Cross-block traffic: sc0 sc1 (device coherence point) — R4-proven primitives.
static __device__ __forceinline__ void g_store8(void* addr, short4v v) {
  asm volatile("global_store_dwordx2 %0, %1, off sc0 sc1" :: "v"(addr), "v"(v) : "memory");
}
static __device__ __forceinline__ void g_store4(void* addr, unsigned v) {
  asm volatile("global_store_dword %0, %1, off sc0 sc1" :: "v"(addr), "v"(v) : "memory");
}
static __device__ __forceinline__ unsigned g_load4w(const void* addr) {  // fused load+wait
  unsigned v;
  asm volatile("global_load_dword %0, %1, off sc0 sc1\n\ts_waitcnt vmcnt(0)"
               : "=v"(v) : "v"(addr) : "memory");
  return v;
}
static __device__ __forceinline__ unsigned g_load4_nw(const void* addr) {  // no wait (speculative)
  unsigned v;
  asm volatile("global_load_dword %0, %1, off sc0 sc1" : "=v"(v) : "v"(addr) : "memory");
  return v;
}
static __device__ __forceinline__ void wait_vm0() {
  asm volatile("s_waitcnt vmcnt(0)" ::: "memory");
}
// lgkm-only barrier: LDS visibility WITHOUT draining global stores.
static __device__ __forceinline__ void bar_lgkm() {
  asm volatile("s_waitcnt lgkmcnt(0)" ::: "memory");
  __builtin_amdgcn_s_barrier();
}

// fast tanh: (e^{2x}-1)/(e^{2x}+1), clamp |x|<=15  (R4-proven accuracy)
static __device__ __forceinline__ float tanh_fast(float x) {
  x = fminf(fmaxf(x, -15.f), 15.f);
  float e = __expf(2.f * x);
  return (e - 1.f) * __builtin_amdgcn_rcpf(e + 1.f);
}

// -------------------- small prep kernels --------------------

__global__ void k_dts(const float* __restrict__ x, float* __restrict__ dts) {
  int s = threadIdx.x;
  if (s < NS - 1) dts[s] = x[(s + 1) * XROW] - x[s * XROW];
  if (s == NS - 1) dts[NS - 1] = x[(NS - 1) * XROW] - x[0];  // sum_dt (telescoping)
}

__global__ void k_y0(const float* __restrict__ x, float* __restrict__ y0) {
  int b = blockIdx.x;
  const float* src = x + (size_t)b * NS * XROW + (size_t)(NS - 1) * XROW + 1;
  for (int d = threadIdx.x; d < NH; d += blockDim.x) y0[b * NH + d] = src[d];
}

__global__ void k_c(const float* __restrict__ W1, const float* __restrict__ b2,
                    float* __restrict__ c) {
  int i = blockIdx.x * blockDim.x + threadIdx.x;
  if (i < NH) {
    float s = 0.f;
    for (int d = 0; d < NH; ++d) s += W1[i * NH + d] * b2[d];
    c[i] = s;
  }
}

__global__ void k_mm_nn_bf16(const float* __restrict__ A, const float* __restrict__ Bm,
                             __hip_bfloat16* __restrict__ C, int N, int K) {
  __shared__ float As[16][17], Bs[16][17];
  int tx = threadIdx.x & 15, ty = threadIdx.x >> 4;
  int m = blockIdx.y * 16 + ty, n = blockIdx.x * 16 + tx;
  float acc = 0.f;
  for (int k0 = 0; k0 < K; k0 += 16) {
    As[ty][tx] = A[m * K + k0 + tx];
    Bs[ty][tx] = Bm[(size_t)(k0 + ty) * N + n];
    __syncthreads();
#pragma unroll
    for (int kk = 0; kk < 16; ++kk) acc += As[ty][kk] * Bs[kk][tx];
    __syncthreads();
  }
  C[m * N + n] = __float2bfloat16(acc);
}

__global__ void k_mm_nn_f32(const float* __restrict__ A, const float* __restrict__ Bm,
                            float* __restrict__ C, int N, int K) {
  __shared__ float As[16][17], Bs[16][17];
  int tx = threadIdx.x & 15, ty = threadIdx.x >> 4;
  int m = blockIdx.y * 16 + ty, n = blockIdx.x * 16 + tx;
  float acc = 0.f;
  for (int k0 = 0; k0 < K; k0 += 16) {
    As[ty][tx] = A[m * K + k0 + tx];
    Bs[ty][tx] = Bm[(size_t)(k0 + ty) * N + n];
    __syncthreads();
#pragma unroll
    for (int kk = 0; kk < 16; ++kk) acc += As[ty][kk] * Bs[kk][tx];
    __syncthreads();
  }
  C[m * N + n] = acc;
}

__global__ void k_mm_nt_f32(const float* __restrict__ A, const float* __restrict__ Bm,
                            float* __restrict__ C, int N, int K) {
  __shared__ float As[16][17], Bs[16][17];
  int tx = threadIdx.x & 15, ty = threadIdx.x >> 4;
  int m = blockIdx.y * 16 + ty;
  int n0 = blockIdx.x * 16;
  float acc = 0.f;
  for (int k0 = 0; k0 < K; k0 += 16) {
    As[ty][tx] = A[m * K + k0 + tx];
    Bs[ty][tx] = Bm[(size_t)(n0 + ty) * K + k0 + tx];
    __syncthreads();
#pragma unroll
    for (int kk = 0; kk < 16; ++kk) acc += As[ty][kk] * Bs[tx][kk];
    __syncthreads();
  }
  C[m * N + n0 + tx] = acc;
}

// -------------------- main ODE integration kernel --------------------
// R13 base (R4 protocol + M-in-registers + fused gather), two latency cuts:
//  (1) DEFERRED ACK: publish -> lgkm-barrier (stores in flight) -> own-k MFMA
//      -> vmcnt(0) (residual) -> flag. Data-before-flag order preserved.
//  (2) SPECULATIVE POLL: flag load issued before own-k MFMA; checked after
//      the ack. Hit -> skip poll loop (~1 RTT saved). Miss/garbage -> fall
//      into R13's proven fused-load poll loop. Liveness never depends on the
//      speculative value. Poll condition is PEERS-ONLY (own-block lanes
//      auto-true) so nobody waits on their own flag's round trip.

__global__ __launch_bounds__(256) void k_main(
    const float* __restrict__ u0, const __hip_bfloat16* __restrict__ Mg,
    const float* __restrict__ cg, const float* __restrict__ b1g,
    const float* __restrict__ dtsg,
    __hip_bfloat16* __restrict__ hG, float* __restrict__ Hacc,
    unsigned int* __restrict__ flags)
{
  __shared__ __hip_bfloat16 hlds[RPC][LPAD];   // 16.25 KB
  __shared__ float dtl[NS];

  const int tid = threadIdx.x;
  const int bx = blockIdx.x;
  const int xcd = bx & 7, slot = bx >> 3;
  const int cl = xcd + ((slot >> 2) << 3);   // cluster members share bid mod 8
  const int jb = slot & 3;
  const int lane = tid & 63, wv = tid >> 6;
  const int r = lane & 15, g4 = lane >> 4;
  const int row0 = cl * RPC;
  const int ub = jb * UBS;
  const int rr = tid >> 4, sl = tid & 15;     // gather assignment

  // ---- M fragments into registers, chunk-reordered: i -> global chunk
  // qg = ((jb + (i>>2)) & 3)*4 + (i&3), so i=0..3 are OWN chunks. ----
  short8 Mreg[2][16];
#pragma unroll
  for (int t = 0; t < 2; ++t)
#pragma unroll
    for (int i = 0; i < 16; ++i) {
      int qg = ((jb + (i >> 2)) & 3) * 4 + (i & 3);
      Mreg[t][i] = *(const short8*)(Mg + (size_t)(ub + wv * 32 + t * 16 + r) * NH
                                    + qg * 32 + g4 * 8);
    }
  if (tid < NS) dtl[tid] = dtsg[tid];

  // per-lane state: (udim = ub + udl0 + t*16 + j, batch row = row0 + r)
  const int udl0 = wv * 32 + g4 * 4;
  float u[2][4], du[2][4], Ht[2][4], hr[2][4], wp[2][4], b1r[2][4], cr[2][4];
#pragma unroll
  for (int t = 0; t < 2; ++t)
#pragma unroll
    for (int j = 0; j < 4; ++j) {
      int ud = ub + udl0 + t * 16 + j;
      u[t][j] = u0[(row0 + r) * NH + ud];
      b1r[t][j] = b1g[ud];
      cr[t][j] = cg[ud];
      Ht[t][j] = 0.f; wp[t][j] = 0.f; du[t][j] = 0.f;
    }
  __syncthreads();

  unsigned int* flg = flags + cl * 32;       // 16 per-wave flag words
  const unsigned int* fp = flg + (lane & 15);
  const bool ownlane = (((lane & 15) >> 2) == jb);   // own block's flag words

  int sidx = 0;
  for (int step = 0; step < NS - 1; ++step) {
    float dt = dtl[step];
#pragma unroll 1
    for (int st = 0; st < 4; ++st, ++sidx) {
      float gam = (st == 0) ? 0.f : ((st == 3) ? dt : 0.5f * dt);
      // h = tanh(u + gam*w_prev + b1)
#pragma unroll
      for (int t = 0; t < 2; ++t)
#pragma unroll
        for (int j = 0; j < 4; ++j)
          hr[t][j] = tanh_fast(u[t][j] + gam * wp[t][j] + b1r[t][j]);

      int par = sidx & 1;
      __hip_bfloat16* hgp = hG + (size_t)(cl * 2 + par) * RPC * NH;
      // publish own h (global stores stay in flight; LDS for own-k MFMA)
#pragma unroll
      for (int t = 0; t < 2; ++t) {
        short4v pk;
        pk.x = (short)bf16bits(hr[t][0]);
        pk.y = (short)bf16bits(hr[t][1]);
        pk.z = (short)bf16bits(hr[t][2]);
        pk.w = (short)bf16bits(hr[t][3]);
        int col = ub + udl0 + t * 16;
        g_store8(hgp + r * NH + col, pk);
        *(short4v*)&hlds[r][col] = pk;
      }
      bar_lgkm();                    // own h visible in LDS; stores in flight

      unsigned tgt = (unsigned)(sidx + 1);
      unsigned specv = g_load4_nw(fp);   // speculative peer-flag load

      // own-k MFMA (publish stores + spec load drain underneath)
      f32x4 acc0 = {0.f, 0.f, 0.f, 0.f}, acc1 = {0.f, 0.f, 0.f, 0.f};
#pragma unroll
      for (int i = 0; i < 4; ++i) {
        int kc = ub + i * 32 + g4 * 8;
        short8 bf = *(const short8*)&hlds[r][kc];
        acc0 = __builtin_amdgcn_mfma_f32_16x16x32_bf16(Mreg[0][i], bf, acc0, 0, 0, 0);
        acc1 = __builtin_amdgcn_mfma_f32_16x16x32_bf16(Mreg[1][i], bf, acc1, 0, 0, 0);
      }

      wait_vm0();                        // ack (residual) + spec load complete
      __builtin_amdgcn_sched_barrier(0); // keep spec check after the wait
      if (lane == 0) g_store4(flg + jb * 4 + wv, tgt);   // per-wave flag

      // peers-only check of speculative value; miss -> proven fused poll loop
      if (!__all((int)(ownlane || (specv >= tgt)))) {
        for (;;) {
          unsigned v = g_load4w(fp);
          if (__all((int)(ownlane || (v >= tgt)))) break;
          __builtin_amdgcn_s_sleep(1);
        }
      }

      // gather 3 remote 4KB chunks: ONE fused asm (loads + wait), then LDS
      {
        int4v d0, d1, d2;
        const __hip_bfloat16* hb = hgp + rr * NH;
        const void* a0 = hb + ((jb + 1) & 3) * UBS + sl * 8;
        const void* a1 = hb + ((jb + 2) & 3) * UBS + sl * 8;
        const void* a2 = hb + ((jb + 3) & 3) * UBS + sl * 8;
        asm volatile(
            "global_load_dwordx4 %0, %3, off sc0 sc1\n\t"
            "global_load_dwordx4 %1, %4, off sc0 sc1\n\t"
            "global_load_dwordx4 %2, %5, off sc0 sc1\n\t"
            "s_waitcnt vmcnt(0)"
            : "=&v"(d0), "=&v"(d1), "=&v"(d2)
            : "v"(a0), "v"(a1), "v"(a2)
            : "memory");
        *(int4v*)&hlds[rr][((jb + 1) & 3) * UBS + sl * 8] = d0;
        *(int4v*)&hlds[rr][((jb + 2) & 3) * UBS + sl * 8] = d1;
        *(int4v*)&hlds[rr][((jb + 3) & 3) * UBS + sl * 8] = d2;
      }
      __syncthreads();                   // remote h visible

      // remote-k MFMA (A from registers, static indices)
#pragma unroll
      for (int m = 1; m < 4; ++m) {
        int jr = (jb + m) & 3;
#pragma unroll
        for (int qq = 0; qq < 4; ++qq) {
          int kc = jr * UBS + qq * 32 + g4 * 8;
          short8 bf = *(const short8*)&hlds[r][kc];
          acc0 = __builtin_amdgcn_mfma_f32_16x16x32_bf16(Mreg[0][m * 4 + qq], bf, acc0, 0, 0, 0);
          acc1 = __builtin_amdgcn_mfma_f32_16x16x32_bf16(Mreg[1][m * 4 + qq], bf, acc1, 0, 0, 0);
        }
      }

      // folded RK4: du += cw*w ; Ht += (dt/6)*cw*h ; wp = w ; st3: u += (dt/6)*du
      {
        float cw = (st == 0 || st == 3) ? 1.f : 2.f;
        float f6 = dt * (1.f / 6.f);
        float f6c = f6 * cw;
#pragma unroll
        for (int j = 0; j < 4; ++j) {
          float w0 = acc0[j] + cr[0][j];
          float w1 = acc1[j] + cr[1][j];
          du[0][j] = (st == 0) ? w0 : du[0][j] + cw * w0;
          du[1][j] = (st == 0) ? w1 : du[1][j] + cw * w1;
          Ht[0][j] += f6c * hr[0][j];
          Ht[1][j] += f6c * hr[1][j];
          wp[0][j] = w0;
          wp[1][j] = w1;
        }
        if (st == 3) {
#pragma unroll
          for (int t = 0; t < 2; ++t)
#pragma unroll
            for (int j = 0; j < 4; ++j)
              u[t][j] += f6 * du[t][j];
        }
      }
    }
  }

  // write out H accumulator
#pragma unroll
  for (int t = 0; t < 2; ++t)
#pragma unroll
    for (int j = 0; j < 4; ++j)
      Hacc[(row0 + r) * NH + ub + udl0 + t * 16 + j] = Ht[t][j];
}

// -------------------- epilogue --------------------
__global__ void k_epi(const float* __restrict__ y0, const float* __restrict__ Hacc,
                      const float* __restrict__ P, const float* __restrict__ Wout,
                      const float* __restrict__ b2, const float* __restrict__ bout,
                      const float* __restrict__ dtsg, float* __restrict__ out)
{
  __shared__ float ys[NH], hs[NH];
  int rr = blockIdx.x, o = threadIdx.x;
  float sdt = dtsg[NS - 1];
  for (int i = threadIdx.x; i < NH; i += blockDim.x) {
    ys[i] = y0[rr * NH + i] + sdt * b2[i];
    hs[i] = Hacc[rr * NH + i];
  }
  __syncthreads();
  float s = bout[o];
  const float* wr = Wout + o * NH;
  const float* pr = P + o * NH;
  for (int d = 0; d < NH; ++d) s += wr[d] * ys[d];
  for (int h = 0; h < NH; ++h) s += pr[h] * hs[h];
  out[rr * NOUT + o] = s;
}

// -------------------- launch --------------------

extern "C" void kernel_launch(void* const* d_in, const int* in_sizes, int n_in,
                              void* d_out, int out_size, void* d_ws, size_t ws_size,
                              hipStream_t stream) {
  const float* x    = (const float*)d_in[0];
  const float* W1   = (const float*)d_in[1];
  const float* b1   = (const float*)d_in[2];
  const float* W2   = (const float*)d_in[3];
  const float* b2   = (const float*)d_in[4];
  const float* Wout = (const float*)d_in[5];
  const float* bout = (const float*)d_in[6];
  float* out = (float*)d_out;

  char* ws = (char*)d_ws;
  float*          dts  = (float*)(ws + OFF_DTS);
  float*          y0   = (float*)(ws + OFF_Y0);
  float*          u0   = (float*)(ws + OFF_U0);
  __hip_bfloat16* Mbf  = (__hip_bfloat16*)(ws + OFF_M);
  float*          cvec = (float*)(ws + OFF_C);
  float*          P    = (float*)(ws + OFF_P);
  __hip_bfloat16* hG   = (__hip_bfloat16*)(ws + OFF_HG);
  float*          Hac  = (float*)(ws + OFF_HACC);
  unsigned int*   flg  = (unsigned int*)(ws + OFF_FLAGS);

  hipMemsetAsync(flg, 0, NCL * 32 * 4, stream);   // monotonic flags start at 0

  k_dts<<<1, 256, 0, stream>>>(x, dts);
  k_y0 <<<NB, 256, 0, stream>>>(x, y0);
  k_c  <<<2, 256, 0, stream>>>(W1, b2, cvec);
  k_mm_nn_bf16<<<dim3(32, 32), 256, 0, stream>>>(W1, W2, Mbf, NH, NH);
  k_mm_nt_f32<<<dim3(32, 16), 256, 0, stream>>>(y0, W1, u0, NH, NH);
  k_mm_nn_f32<<<dim3(32, 8), 256, 0, stream>>>(Wout, W2, P, NH, NH);

  k_main<<<NCL * BPC, 256, 0, stream>>>(u0, Mbf, cvec, b1, dts, hG, Hac, flg);

  k_epi<<<NB, NOUT, 0, stream>>>(y0, Hac, P, Wout, b2, bout, dts, out);
}